// Round 8
// baseline (93.946 us; speedup 1.0000x reference)
//
#include <hip/hip_runtime.h>
#include <math.h>

// Problem constants: gts/preds [4, 8192, 3] fp32; out [4] fp32.
#define BB 4
#define NPTS 8192
#define THREADS 256
#define NQ_TOTAL (2 * BB * NPTS)       // 65536 points (each set packed once)
#define SLICES 4                       // ref-dim split (occupancy: 8 blocks/CU)
#define RPS (NPTS / SLICES)            // 2048 refs per slice
#define TILES (NPTS / 32)              // 256 query tiles per (dir,b)
#define NWAVES (SLICES * 2 * BB * TILES)   // 8192 waves
#define NBLK_MIN (NWAVES / 4)          // 2048 blocks (4 waves each)

typedef __attribute__((ext_vector_type(8)))  short bf16x8;   // MFMA A/B frag
typedef __attribute__((ext_vector_type(16))) float f32x16;   // MFMA C/D frag

// ws layout:
//   refpack: NQ_TOTAL uint4  bf16 [x,y,z,rr_hi,rr_lo,1,1,0]       1 MiB
//   qpack:   NQ_TOTAL uint4  bf16 [-2x,-2y,-2z,1,1,qq_hi,qq_lo,0] 1 MiB
//   minpart: SLICES * NQ_TOTAL float                              1 MiB
// MFMA dot(A_row, B_col) = -2 q.r + rr + qq = |q-r|^2 (on bf16-rounded pts).

__device__ __forceinline__ unsigned short f2bf(float f) {   // RNE f32->bf16
    unsigned u = __float_as_uint(f);
    u += 0x7FFF + ((u >> 16) & 1);
    return (unsigned short)(u >> 16);
}
__device__ __forceinline__ float bf2f(unsigned short h) {
    return __uint_as_float(((unsigned)h) << 16);
}

// ---------------------------------------------------------------------------
// Kernel 1: round coords to bf16, build A- and B-side fragments; zero out[].
// rr/qq computed in fp32 FROM THE ROUNDED coords and fed as 2-term bf16
// splits, so d^2 = |q~-r~|^2 up to ~2^-17 relative error.
// ---------------------------------------------------------------------------
__global__ __launch_bounds__(THREADS) void pack_kernel(
    const float* __restrict__ gts, const float* __restrict__ preds,
    uint4* __restrict__ refpack, uint4* __restrict__ qpack,
    float* __restrict__ out) {
    int idx = blockIdx.x * THREADS + threadIdx.x;
    if (idx < BB) out[idx] = 0.0f;
    if (idx >= NQ_TOTAL) return;
    int set  = idx / (BB * NPTS);          // 0 = gts, 1 = preds
    int pidx = idx - set * (BB * NPTS);
    const float* src = set ? preds : gts;
    unsigned short hx = f2bf(src[pidx * 3 + 0]);
    unsigned short hy = f2bf(src[pidx * 3 + 1]);
    unsigned short hz = f2bf(src[pidx * 3 + 2]);
    float fx = bf2f(hx), fy = bf2f(hy), fz = bf2f(hz);
    float rr = fmaf(fx, fx, fmaf(fy, fy, fz * fz));
    unsigned short hrr = f2bf(rr);
    unsigned short hlo = f2bf(rr - bf2f(hrr));
    const unsigned short ONE = 0x3F80;      // 1.0 bf16

    uint4 rv;                               // B slots: [x,y,z,rrhi,rrlo,1,1,0]
    rv.x = (unsigned)hx  | ((unsigned)hy  << 16);
    rv.y = (unsigned)hz  | ((unsigned)hrr << 16);
    rv.z = (unsigned)hlo | ((unsigned)ONE << 16);
    rv.w = (unsigned)ONE;
    refpack[idx] = rv;

    unsigned short nx = f2bf(-2.0f * fx);   // exact (coords already bf16)
    unsigned short ny = f2bf(-2.0f * fy);
    unsigned short nz = f2bf(-2.0f * fz);
    uint4 qv;                               // A slots: [-2x,-2y,-2z,1,1,qqhi,qqlo,0]
    qv.x = (unsigned)nx  | ((unsigned)ny  << 16);
    qv.y = (unsigned)nz  | ((unsigned)ONE << 16);
    qv.z = (unsigned)ONE | ((unsigned)hrr << 16);
    qv.w = (unsigned)hlo;
    qpack[idx] = qv;
}

// ---------------------------------------------------------------------------
// Kernel 2: MFMA min kernel. One wave owns 32 queries (A, persistent, K slots
// 8-15 zero) and scans RPS refs, 64/iter (two B tiles vs the same A). A's
// upper K slots are zero -> B's lanes 32-63 are don't-care -> unconditional
// full-wave loads, no exec mask. Two MFMA results merge via min3 -> 0.5 VALU
// ops/pair. SLICES=4 gives 2048 blocks = 8/CU = full 32 waves/CU occupancy
// to hide MFMA->min3 dependency latency.
// D layout (m74/m101): col = lane&31, row = (r&3)+8*(r>>2)+4*(lane>>5).
// ---------------------------------------------------------------------------
__global__ __launch_bounds__(THREADS) void min_kernel(
    const uint4* __restrict__ refpack, const uint4* __restrict__ qpack,
    float* __restrict__ minpart) {
    int wid  = threadIdx.x >> 6;
    int lane = threadIdx.x & 63;
    int gw   = blockIdx.x * 4 + wid;       // 0 .. NWAVES-1
    int slice = gw >> 11;                  // / (2*BB*TILES)
    int rem   = gw & 2047;
    int dir   = rem >> 10;
    int b     = (rem >> 8) & 3;
    int tile  = rem & 255;
    int qset  = dir ^ 1;                   // dir0: queries=preds(set1), refs=gts
    int rset  = dir;

    size_t qoff = (size_t)(qset * BB + b) * NPTS + (size_t)tile * 32;
    size_t roff = (size_t)(rset * BB + b) * NPTS + (size_t)slice * RPS;
    int l31  = lane & 31;
    int half = lane >> 5;

    // A fragment: lanes 0-31 = query l31 (K slots 0-7); lanes 32-63 = zero.
    bf16x8 a = {0, 0, 0, 0, 0, 0, 0, 0};
    if (lane < 32) a = ((const bf16x8*)qpack)[qoff + l31];

    f32x16 zeroc;
    #pragma unroll
    for (int r = 0; r < 16; ++r) zeroc[r] = 0.0f;

    float macc[16];
    #pragma unroll
    for (int r = 0; r < 16; ++r) macc[r] = 3.0e38f;

    const bf16x8* rp = (const bf16x8*)refpack + roff;
    #pragma unroll 4
    for (int t = 0; t < RPS / 64; ++t) {   // 64 refs per iter, 32 iters
        bf16x8 b0 = rp[l31];
        bf16x8 b1 = rp[l31 + 32];
        rp += 64;
        f32x16 d0 = __builtin_amdgcn_mfma_f32_32x32x16_bf16(a, b0, zeroc, 0, 0, 0);
        f32x16 d1 = __builtin_amdgcn_mfma_f32_32x32x16_bf16(a, b1, zeroc, 0, 0, 0);
        #pragma unroll
        for (int r = 0; r < 16; ++r)
            macc[r] = fminf(fminf(d0[r], d1[r]), macc[r]);   // -> v_min3_f32
    }

    // Min across the 32 cols (lanes within each half), per row register.
    #pragma unroll
    for (int s = 1; s <= 16; s <<= 1) {
        #pragma unroll
        for (int r = 0; r < 16; ++r)
            macc[r] = fminf(macc[r], __shfl_xor(macc[r], s, 64));
    }

    // Lane r of each half writes row(r, half).
    float* mp = minpart + (size_t)slice * NQ_TOTAL
              + (size_t)(dir * BB + b) * NPTS + (size_t)tile * 32;
    #pragma unroll
    for (int r = 0; r < 16; ++r) {
        int row = (r & 3) + 8 * (r >> 2) + 4 * half;
        if (l31 == r) mp[row] = macc[r];
    }
}

// ---------------------------------------------------------------------------
// Kernel 3: merge slices, sqrt, block-reduce, atomicAdd into out[b].
// ---------------------------------------------------------------------------
__global__ __launch_bounds__(THREADS) void merge_kernel(
    const float* __restrict__ minpart, float* __restrict__ out) {
    int q = blockIdx.x * THREADS + threadIdx.x;    // 0 .. NQ_TOTAL-1
    float m = minpart[q];
    #pragma unroll
    for (int s = 1; s < SLICES; ++s)
        m = fminf(m, minpart[(size_t)s * NQ_TOTAL + q]);
    float d = sqrtf(fmaxf(m, 0.0f));
    int b = (q >> 13) & 3;                         // uniform within a block

    float sum = d;
    #pragma unroll
    for (int off = 32; off > 0; off >>= 1)
        sum += __shfl_down(sum, off, 64);

    __shared__ float wsum[THREADS / 64];
    int lane = threadIdx.x & 63;
    int wid  = threadIdx.x >> 6;
    if (lane == 0) wsum[wid] = sum;
    __syncthreads();
    if (threadIdx.x == 0)
        atomicAdd(out + b, wsum[0] + wsum[1] + wsum[2] + wsum[3]);
}

extern "C" void kernel_launch(void* const* d_in, const int* in_sizes, int n_in,
                              void* d_out, int out_size, void* d_ws, size_t ws_size,
                              hipStream_t stream) {
    const float* gts   = (const float*)d_in[0];
    const float* preds = (const float*)d_in[1];
    float* out = (float*)d_out;

    char* ws = (char*)d_ws;
    uint4* refpack = (uint4*)ws;                                   // 1 MiB
    uint4* qpack   = (uint4*)(ws + (size_t)NQ_TOTAL * 16);         // 1 MiB
    float* minpart = (float*)(ws + (size_t)NQ_TOTAL * 32);         // 1 MiB

    pack_kernel<<<NQ_TOTAL / THREADS, THREADS, 0, stream>>>(
        gts, preds, refpack, qpack, out);

    min_kernel<<<NBLK_MIN, THREADS, 0, stream>>>(refpack, qpack, minpart);

    merge_kernel<<<NQ_TOTAL / THREADS, THREADS, 0, stream>>>(minpart, out);
}

// Round 9
// 90.284 us; speedup vs baseline: 1.0406x; 1.0406x over previous
//
#include <hip/hip_runtime.h>
#include <math.h>

// Problem constants: gts/preds [4, 8192, 3] fp32; out [4] fp32.
#define BB 4
#define NPTS 8192
#define THREADS 256
#define NQ_TOTAL (2 * BB * NPTS)       // 65536 points (each set packed once)
#define SLICES 4                       // ref-dim split
#define RPS (NPTS / SLICES)            // 2048 refs per slice
#define QPW 64                         // queries per wave (2 MFMA row-tiles)
#define QTILES (NPTS / QPW)            // 128 query groups per (dir,b)
#define NWAVES (SLICES * 2 * BB * QTILES)  // 4096 waves (4 per SIMD)
#define NBLK_MIN (NWAVES / 4)          // 1024 blocks (4 waves each)

typedef __attribute__((ext_vector_type(8)))  short bf16x8;   // MFMA A/B frag
typedef __attribute__((ext_vector_type(16))) float f32x16;   // MFMA C/D frag

// ws layout:
//   refpack: NQ_TOTAL uint4  bf16 [x,y,z,rr_hi,rr_lo,1,1,0]       1 MiB
//   qpack:   NQ_TOTAL uint4  bf16 [-2x,-2y,-2z,1,1,qq_hi,qq_lo,0] 1 MiB
//   minpart: SLICES * NQ_TOTAL float                              1 MiB
// MFMA dot(A_row, B_col) = -2 q.r + rr + qq = |q-r|^2 (on bf16-rounded pts).

__device__ __forceinline__ unsigned short f2bf(float f) {   // RNE f32->bf16
    unsigned u = __float_as_uint(f);
    u += 0x7FFF + ((u >> 16) & 1);
    return (unsigned short)(u >> 16);
}
__device__ __forceinline__ float bf2f(unsigned short h) {
    return __uint_as_float(((unsigned)h) << 16);
}

// ---------------------------------------------------------------------------
// Kernel 1: round coords to bf16, build A- and B-side fragments; zero out[].
// rr/qq computed in fp32 FROM THE ROUNDED coords and fed as 2-term bf16
// splits, so d^2 = |q~-r~|^2 up to ~2^-17 relative error.
// ---------------------------------------------------------------------------
__global__ __launch_bounds__(THREADS) void pack_kernel(
    const float* __restrict__ gts, const float* __restrict__ preds,
    uint4* __restrict__ refpack, uint4* __restrict__ qpack,
    float* __restrict__ out) {
    int idx = blockIdx.x * THREADS + threadIdx.x;
    if (idx < BB) out[idx] = 0.0f;
    if (idx >= NQ_TOTAL) return;
    int set  = idx / (BB * NPTS);          // 0 = gts, 1 = preds
    int pidx = idx - set * (BB * NPTS);
    const float* src = set ? preds : gts;
    unsigned short hx = f2bf(src[pidx * 3 + 0]);
    unsigned short hy = f2bf(src[pidx * 3 + 1]);
    unsigned short hz = f2bf(src[pidx * 3 + 2]);
    float fx = bf2f(hx), fy = bf2f(hy), fz = bf2f(hz);
    float rr = fmaf(fx, fx, fmaf(fy, fy, fz * fz));
    unsigned short hrr = f2bf(rr);
    unsigned short hlo = f2bf(rr - bf2f(hrr));
    const unsigned short ONE = 0x3F80;      // 1.0 bf16

    uint4 rv;                               // B slots: [x,y,z,rrhi,rrlo,1,1,0]
    rv.x = (unsigned)hx  | ((unsigned)hy  << 16);
    rv.y = (unsigned)hz  | ((unsigned)hrr << 16);
    rv.z = (unsigned)hlo | ((unsigned)ONE << 16);
    rv.w = (unsigned)ONE;
    refpack[idx] = rv;

    unsigned short nx = f2bf(-2.0f * fx);   // exact (coords already bf16)
    unsigned short ny = f2bf(-2.0f * fy);
    unsigned short nz = f2bf(-2.0f * fz);
    uint4 qv;                               // A slots: [-2x,-2y,-2z,1,1,qqhi,qqlo,0]
    qv.x = (unsigned)nx  | ((unsigned)ny  << 16);
    qv.y = (unsigned)nz  | ((unsigned)ONE << 16);
    qv.z = (unsigned)ONE | ((unsigned)hrr << 16);
    qv.w = (unsigned)hlo;
    qpack[idx] = qv;
}

// ---------------------------------------------------------------------------
// Kernel 2: MFMA min kernel, L1-BW-optimized. One wave owns 64 queries as TWO
// persistent A fragments; each iter loads two B tiles (64 refs) and issues
// FOUR MFMAs -> every loaded byte feeds 2x the pairs of R7 (L1 floor halves).
// A's K slots 8-15 are zero -> B lanes 32-63 are don't-care -> unconditional
// full-wave loads. Per-pair VALU: 0.5 v_min3.
// D layout (m74/m101): col = lane&31, row = (r&3)+8*(r>>2)+4*(lane>>5).
// ---------------------------------------------------------------------------
__global__ __launch_bounds__(THREADS) void min_kernel(
    const uint4* __restrict__ refpack, const uint4* __restrict__ qpack,
    float* __restrict__ minpart) {
    int wid  = threadIdx.x >> 6;
    int lane = threadIdx.x & 63;
    int gw   = blockIdx.x * 4 + wid;       // 0 .. NWAVES-1
    int slice = gw >> 10;                  // / (2*BB*QTILES) = /1024
    int rem   = gw & 1023;
    int dir   = rem >> 9;
    int b     = (rem >> 7) & 3;
    int qt    = rem & 127;                 // query group (64 queries)
    int qset  = dir ^ 1;                   // dir0: queries=preds(set1), refs=gts
    int rset  = dir;

    size_t qoff = (size_t)(qset * BB + b) * NPTS + (size_t)qt * QPW;
    size_t roff = (size_t)(rset * BB + b) * NPTS + (size_t)slice * RPS;
    int l31  = lane & 31;
    int half = lane >> 5;

    // Two A fragments: lanes 0-31 = query rows (K slots 0-7); lanes 32-63 = 0.
    bf16x8 a0 = {0, 0, 0, 0, 0, 0, 0, 0};
    bf16x8 a1 = {0, 0, 0, 0, 0, 0, 0, 0};
    if (lane < 32) {
        a0 = ((const bf16x8*)qpack)[qoff + l31];
        a1 = ((const bf16x8*)qpack)[qoff + 32 + l31];
    }

    f32x16 zeroc;
    #pragma unroll
    for (int r = 0; r < 16; ++r) zeroc[r] = 0.0f;

    float macc0[16], macc1[16];
    #pragma unroll
    for (int r = 0; r < 16; ++r) { macc0[r] = 3.0e38f; macc1[r] = 3.0e38f; }

    const bf16x8* rp = (const bf16x8*)refpack + roff;
    #pragma unroll 2
    for (int t = 0; t < RPS / 64; ++t) {   // 64 refs x 64 queries per iter
        bf16x8 b0 = rp[l31];
        bf16x8 b1 = rp[l31 + 32];
        rp += 64;
        f32x16 d00 = __builtin_amdgcn_mfma_f32_32x32x16_bf16(a0, b0, zeroc, 0, 0, 0);
        f32x16 d01 = __builtin_amdgcn_mfma_f32_32x32x16_bf16(a0, b1, zeroc, 0, 0, 0);
        #pragma unroll
        for (int r = 0; r < 16; ++r)
            macc0[r] = fminf(fminf(d00[r], d01[r]), macc0[r]);   // v_min3_f32
        f32x16 d10 = __builtin_amdgcn_mfma_f32_32x32x16_bf16(a1, b0, zeroc, 0, 0, 0);
        f32x16 d11 = __builtin_amdgcn_mfma_f32_32x32x16_bf16(a1, b1, zeroc, 0, 0, 0);
        #pragma unroll
        for (int r = 0; r < 16; ++r)
            macc1[r] = fminf(fminf(d10[r], d11[r]), macc1[r]);
    }

    // Min across the 32 cols (lanes within each half), per row register.
    #pragma unroll
    for (int s = 1; s <= 16; s <<= 1) {
        #pragma unroll
        for (int r = 0; r < 16; ++r) {
            macc0[r] = fminf(macc0[r], __shfl_xor(macc0[r], s, 64));
            macc1[r] = fminf(macc1[r], __shfl_xor(macc1[r], s, 64));
        }
    }

    // Lane r of each half writes row(r, half), for both query tiles.
    float* mp = minpart + (size_t)slice * NQ_TOTAL
              + (size_t)(dir * BB + b) * NPTS + (size_t)qt * QPW;
    #pragma unroll
    for (int r = 0; r < 16; ++r) {
        int row = (r & 3) + 8 * (r >> 2) + 4 * half;
        if (l31 == r) {
            mp[row]      = macc0[r];
            mp[row + 32] = macc1[r];
        }
    }
}

// ---------------------------------------------------------------------------
// Kernel 3: merge slices, sqrt, block-reduce, atomicAdd into out[b].
// ---------------------------------------------------------------------------
__global__ __launch_bounds__(THREADS) void merge_kernel(
    const float* __restrict__ minpart, float* __restrict__ out) {
    int q = blockIdx.x * THREADS + threadIdx.x;    // 0 .. NQ_TOTAL-1
    float m = minpart[q];
    #pragma unroll
    for (int s = 1; s < SLICES; ++s)
        m = fminf(m, minpart[(size_t)s * NQ_TOTAL + q]);
    float d = sqrtf(fmaxf(m, 0.0f));
    int b = (q >> 13) & 3;                         // uniform within a block

    float sum = d;
    #pragma unroll
    for (int off = 32; off > 0; off >>= 1)
        sum += __shfl_down(sum, off, 64);

    __shared__ float wsum[THREADS / 64];
    int lane = threadIdx.x & 63;
    int wid  = threadIdx.x >> 6;
    if (lane == 0) wsum[wid] = sum;
    __syncthreads();
    if (threadIdx.x == 0)
        atomicAdd(out + b, wsum[0] + wsum[1] + wsum[2] + wsum[3]);
}

extern "C" void kernel_launch(void* const* d_in, const int* in_sizes, int n_in,
                              void* d_out, int out_size, void* d_ws, size_t ws_size,
                              hipStream_t stream) {
    const float* gts   = (const float*)d_in[0];
    const float* preds = (const float*)d_in[1];
    float* out = (float*)d_out;

    char* ws = (char*)d_ws;
    uint4* refpack = (uint4*)ws;                                   // 1 MiB
    uint4* qpack   = (uint4*)(ws + (size_t)NQ_TOTAL * 16);         // 1 MiB
    float* minpart = (float*)(ws + (size_t)NQ_TOTAL * 32);         // 1 MiB

    pack_kernel<<<NQ_TOTAL / THREADS, THREADS, 0, stream>>>(
        gts, preds, refpack, qpack, out);

    min_kernel<<<NBLK_MIN, THREADS, 0, stream>>>(refpack, qpack, minpart);

    merge_kernel<<<NQ_TOTAL / THREADS, THREADS, 0, stream>>>(minpart, out);
}

// Round 10
// 88.406 us; speedup vs baseline: 1.0627x; 1.0212x over previous
//
#include <hip/hip_runtime.h>
#include <math.h>

// Problem constants: gts/preds [4, 8192, 3] fp32; out [4] fp32.
#define BB 4
#define NPTS 8192
#define THREADS 256
#define NQ_TOTAL (2 * BB * NPTS)       // 65536 points (each set packed once)
#define SLICES 4                       // ref-dim split; 32 KB LDS per block
#define RPS (NPTS / SLICES)            // 2048 refs per slice
#define QPB_MIN 256                    // queries per block (4 waves x 64)
#define QGROUPS (NPTS / QPB_MIN)       // 32 query groups per (dir,b)
#define NBLK_MIN (SLICES * 2 * BB * QGROUPS)   // 1024 blocks

typedef __attribute__((ext_vector_type(8)))  short bf16x8;   // MFMA A/B frag
typedef __attribute__((ext_vector_type(16))) float f32x16;   // MFMA C/D frag

// ws layout:
//   refpack: NQ_TOTAL uint4  bf16 [x,y,z,rr_hi,rr_lo,1,1,0]       1 MiB
//   qpack:   NQ_TOTAL uint4  bf16 [-2x,-2y,-2z,1,1,qq_hi,qq_lo,0] 1 MiB
//   minpart: SLICES * NQ_TOTAL float                              1 MiB
// MFMA dot(A_row, B_col) = -2 q.r + rr + qq = |q-r|^2 (on bf16-rounded pts).

__device__ __forceinline__ unsigned short f2bf(float f) {   // RNE f32->bf16
    unsigned u = __float_as_uint(f);
    u += 0x7FFF + ((u >> 16) & 1);
    return (unsigned short)(u >> 16);
}
__device__ __forceinline__ float bf2f(unsigned short h) {
    return __uint_as_float(((unsigned)h) << 16);
}

// ---------------------------------------------------------------------------
// Kernel 1: round coords to bf16, build A- and B-side fragments; zero out[].
// rr/qq computed in fp32 FROM THE ROUNDED coords and fed as 2-term bf16
// splits, so d^2 = |q~-r~|^2 up to ~2^-17 relative error.
// ---------------------------------------------------------------------------
__global__ __launch_bounds__(THREADS) void pack_kernel(
    const float* __restrict__ gts, const float* __restrict__ preds,
    uint4* __restrict__ refpack, uint4* __restrict__ qpack,
    float* __restrict__ out) {
    int idx = blockIdx.x * THREADS + threadIdx.x;
    if (idx < BB) out[idx] = 0.0f;
    if (idx >= NQ_TOTAL) return;
    int set  = idx / (BB * NPTS);          // 0 = gts, 1 = preds
    int pidx = idx - set * (BB * NPTS);
    const float* src = set ? preds : gts;
    unsigned short hx = f2bf(src[pidx * 3 + 0]);
    unsigned short hy = f2bf(src[pidx * 3 + 1]);
    unsigned short hz = f2bf(src[pidx * 3 + 2]);
    float fx = bf2f(hx), fy = bf2f(hy), fz = bf2f(hz);
    float rr = fmaf(fx, fx, fmaf(fy, fy, fz * fz));
    unsigned short hrr = f2bf(rr);
    unsigned short hlo = f2bf(rr - bf2f(hrr));
    const unsigned short ONE = 0x3F80;      // 1.0 bf16

    uint4 rv;                               // B slots: [x,y,z,rrhi,rrlo,1,1,0]
    rv.x = (unsigned)hx  | ((unsigned)hy  << 16);
    rv.y = (unsigned)hz  | ((unsigned)hrr << 16);
    rv.z = (unsigned)hlo | ((unsigned)ONE << 16);
    rv.w = (unsigned)ONE;
    refpack[idx] = rv;

    unsigned short nx = f2bf(-2.0f * fx);   // exact (coords already bf16)
    unsigned short ny = f2bf(-2.0f * fy);
    unsigned short nz = f2bf(-2.0f * fz);
    uint4 qv;                               // A slots: [-2x,-2y,-2z,1,1,qqhi,qqlo,0]
    qv.x = (unsigned)nx  | ((unsigned)ny  << 16);
    qv.y = (unsigned)nz  | ((unsigned)ONE << 16);
    qv.z = (unsigned)ONE | ((unsigned)hrr << 16);
    qv.w = (unsigned)hlo;
    qpack[idx] = qv;
}

// ---------------------------------------------------------------------------
// Kernel 2: MFMA min kernel, LDS-staged. Each block (4 waves, 256 queries)
// stages its 32 KB ref slice into LDS once (coalesced global loads, one
// barrier), then scans it with ds_read_b128 (~120 cyc, fine-grained lgkmcnt)
// instead of per-lane global loads (~200+ cyc, vmcnt stalls) — attacking the
// measured latency exposure. Per iter: 2 ds_reads feed 4 MFMAs (2 persistent
// A frags); 0.5 v_min3 per pair. A's K slots 8-15 are zero -> B lanes 32-63
// are don't-care -> unconditional full-wave reads.
// D layout (m74/m101): col = lane&31, row = (r&3)+8*(r>>2)+4*(lane>>5).
// ---------------------------------------------------------------------------
__global__ __launch_bounds__(THREADS) void min_kernel(
    const uint4* __restrict__ refpack, const uint4* __restrict__ qpack,
    float* __restrict__ minpart) {
    __shared__ uint4 sref[RPS];            // 32 KB

    int tid   = threadIdx.x;
    int blk   = blockIdx.x;
    int slice = blk >> 8;                  // / (2*BB*QGROUPS) = /256
    int rem   = blk & 255;
    int dir   = rem >> 7;
    int b     = (rem >> 5) & 3;
    int qg    = rem & 31;                  // query group of 256
    int qset  = dir ^ 1;                   // dir0: queries=preds(set1), refs=gts
    int rset  = dir;

    // Stage the ref slice: 2048 uint4, 8 coalesced rounds of 256 lanes.
    const uint4* rgl = refpack + (size_t)(rset * BB + b) * NPTS
                     + (size_t)slice * RPS;
    #pragma unroll
    for (int i = 0; i < RPS / THREADS; ++i)
        sref[i * THREADS + tid] = rgl[i * THREADS + tid];
    __syncthreads();

    int wid  = tid >> 6;
    int lane = tid & 63;
    int l31  = lane & 31;
    int half = lane >> 5;

    // Two persistent A fragments (64 queries per wave).
    size_t qoff = (size_t)(qset * BB + b) * NPTS + (size_t)qg * QPB_MIN
                + (size_t)wid * 64;
    bf16x8 a0 = {0, 0, 0, 0, 0, 0, 0, 0};
    bf16x8 a1 = {0, 0, 0, 0, 0, 0, 0, 0};
    if (lane < 32) {
        a0 = ((const bf16x8*)qpack)[qoff + l31];
        a1 = ((const bf16x8*)qpack)[qoff + 32 + l31];
    }

    f32x16 zeroc;
    #pragma unroll
    for (int r = 0; r < 16; ++r) zeroc[r] = 0.0f;

    float macc0[16], macc1[16];
    #pragma unroll
    for (int r = 0; r < 16; ++r) { macc0[r] = 3.0e38f; macc1[r] = 3.0e38f; }

    const bf16x8* sp = (const bf16x8*)sref;
    #pragma unroll 2
    for (int t = 0; t < RPS / 64; ++t) {   // 64 refs x 64 queries per iter
        bf16x8 b0 = sp[t * 64 + l31];
        bf16x8 b1 = sp[t * 64 + l31 + 32];
        f32x16 d00 = __builtin_amdgcn_mfma_f32_32x32x16_bf16(a0, b0, zeroc, 0, 0, 0);
        f32x16 d01 = __builtin_amdgcn_mfma_f32_32x32x16_bf16(a0, b1, zeroc, 0, 0, 0);
        #pragma unroll
        for (int r = 0; r < 16; ++r)
            macc0[r] = fminf(fminf(d00[r], d01[r]), macc0[r]);   // v_min3_f32
        f32x16 d10 = __builtin_amdgcn_mfma_f32_32x32x16_bf16(a1, b0, zeroc, 0, 0, 0);
        f32x16 d11 = __builtin_amdgcn_mfma_f32_32x32x16_bf16(a1, b1, zeroc, 0, 0, 0);
        #pragma unroll
        for (int r = 0; r < 16; ++r)
            macc1[r] = fminf(fminf(d10[r], d11[r]), macc1[r]);
    }

    // Min across the 32 cols (lanes within each half), per row register.
    #pragma unroll
    for (int s = 1; s <= 16; s <<= 1) {
        #pragma unroll
        for (int r = 0; r < 16; ++r) {
            macc0[r] = fminf(macc0[r], __shfl_xor(macc0[r], s, 64));
            macc1[r] = fminf(macc1[r], __shfl_xor(macc1[r], s, 64));
        }
    }

    // Lane r of each half writes row(r, half), for both query tiles.
    float* mp = minpart + (size_t)slice * NQ_TOTAL
              + (size_t)(dir * BB + b) * NPTS + (size_t)qg * QPB_MIN
              + (size_t)wid * 64;
    #pragma unroll
    for (int r = 0; r < 16; ++r) {
        int row = (r & 3) + 8 * (r >> 2) + 4 * half;
        if (l31 == r) {
            mp[row]      = macc0[r];
            mp[row + 32] = macc1[r];
        }
    }
}

// ---------------------------------------------------------------------------
// Kernel 3: merge slices, sqrt, block-reduce, atomicAdd into out[b].
// ---------------------------------------------------------------------------
__global__ __launch_bounds__(THREADS) void merge_kernel(
    const float* __restrict__ minpart, float* __restrict__ out) {
    int q = blockIdx.x * THREADS + threadIdx.x;    // 0 .. NQ_TOTAL-1
    float m = minpart[q];
    #pragma unroll
    for (int s = 1; s < SLICES; ++s)
        m = fminf(m, minpart[(size_t)s * NQ_TOTAL + q]);
    float d = sqrtf(fmaxf(m, 0.0f));
    int b = (q >> 13) & 3;                         // uniform within a block

    float sum = d;
    #pragma unroll
    for (int off = 32; off > 0; off >>= 1)
        sum += __shfl_down(sum, off, 64);

    __shared__ float wsum[THREADS / 64];
    int lane = threadIdx.x & 63;
    int wid  = threadIdx.x >> 6;
    if (lane == 0) wsum[wid] = sum;
    __syncthreads();
    if (threadIdx.x == 0)
        atomicAdd(out + b, wsum[0] + wsum[1] + wsum[2] + wsum[3]);
}

extern "C" void kernel_launch(void* const* d_in, const int* in_sizes, int n_in,
                              void* d_out, int out_size, void* d_ws, size_t ws_size,
                              hipStream_t stream) {
    const float* gts   = (const float*)d_in[0];
    const float* preds = (const float*)d_in[1];
    float* out = (float*)d_out;

    char* ws = (char*)d_ws;
    uint4* refpack = (uint4*)ws;                                   // 1 MiB
    uint4* qpack   = (uint4*)(ws + (size_t)NQ_TOTAL * 16);         // 1 MiB
    float* minpart = (float*)(ws + (size_t)NQ_TOTAL * 32);         // 1 MiB

    pack_kernel<<<NQ_TOTAL / THREADS, THREADS, 0, stream>>>(
        gts, preds, refpack, qpack, out);

    min_kernel<<<NBLK_MIN, THREADS, 0, stream>>>(refpack, qpack, minpart);

    merge_kernel<<<NQ_TOTAL / THREADS, THREADS, 0, stream>>>(minpart, out);
}